// Round 9
// baseline (196.672 us; speedup 1.0000x reference)
//
#include <hip/hip_runtime.h>
#include <math.h>

// L=4096, N=16, H=16, E=64. rho = L*N = 65536 rows of 1024 floats (head h at +64h).
// out[rho][h][f] = exp2( x.Ps[h][:,f] - sq*SQS ) + 1e-6, Ps = proj*64^-.25*log2e.
// proj = q^T D, D = sign(diag(r)) of LAPACK-convention QR(pm[h]^T) (convention-
// dependent — must reproduce geqrf signs). Factor then Q = M R^-1.
// favor: f16 hi/lo split MFMA (C = Xh*Bh + Xh*Bl + Xl*Bh), residual ~2^-23.
// Round-9: 64-row tiles, 32 KB LDS, B-frags from global (no Ps LDS), zero
// barriers, 4 blocks/CU (16 waves/CU) — attacks round-8's latency-bound 2/SIMD.

typedef _Float16 f16x8 __attribute__((ext_vector_type(8)));
typedef float    f32x4 __attribute__((ext_vector_type(4)));

#define AS1 __attribute__((address_space(1)))
#define AS3 __attribute__((address_space(3)))

#if __has_builtin(__builtin_amdgcn_exp2f)
#define EXP2F(x) __builtin_amdgcn_exp2f(x)
#else
#define EXP2F(x) exp2f(x)
#endif

static __device__ __forceinline__ void gload16(const float* g, float* l) {
    __builtin_amdgcn_global_load_lds((AS1 const void*)g, (AS3 void*)l, 16, 0, 0);
}

// ---------------- per-head QR (fp32 Householder, LAPACK dlarfg signs) -------
__global__ __launch_bounds__(256) void qr_kernel(const float* __restrict__ pm,
                                                 float* __restrict__ P)
{
    __shared__ float colb[2][64];
    __shared__ float nrmb[2];
    __shared__ float Rs[64 * 65];
    __shared__ float qcol[2][64];
    __shared__ float dval[64];
    __shared__ float dinv[64];
    __shared__ float sgnNZ[64];

    const int tid = threadIdx.x;
    const int h   = blockIdx.x;
    const int c   = tid >> 2;       // column 0..63 (quad = 4 consecutive lanes)
    const int q   = tid & 3;        // row-quarter
    const int i0  = q * 16;

    float A[16], M[16];             // A[k] = M[i0+k][c] = pm[h][c][i0+k]
    {
        const float4* src = reinterpret_cast<const float4*>(pm + h * 4096 + c * 64 + i0);
        #pragma unroll
        for (int k4 = 0; k4 < 4; ++k4) {
            const float4 v = src[k4];
            A[4*k4+0] = M[4*k4+0] = v.x;
            A[4*k4+1] = M[4*k4+1] = v.y;
            A[4*k4+2] = M[4*k4+2] = v.z;
            A[4*k4+3] = M[4*k4+3] = v.w;
        }
    }
    if (c == 0) {                    // publish column 0 + its sub-norm
        #pragma unroll
        for (int k = 0; k < 16; ++k) colb[0][i0 + k] = A[k];
        float np = 0.f;
        #pragma unroll
        for (int k = 0; k < 16; ++k) if (i0 + k >= 1) np = fmaf(A[k], A[k], np);
        np += __shfl_xor(np, 1); np += __shfl_xor(np, 2);
        if (q == 0) nrmb[0] = np;
    }
    __syncthreads();

    // ---- factor: 64 Householder steps, 1 barrier each ----
    #pragma unroll 1
    for (int j = 0; j < 64; ++j) {
        const float* cbuf = colb[j & 1];
        const float alpha = cbuf[j];
        const float nrm2  = nrmb[j & 1];
        float beta, g;
        if (nrm2 == 0.f) { beta = alpha; g = 0.f; }          // H = I, tau = 0
        else {
            const float an = sqrtf(fmaf(alpha, alpha, nrm2));
            beta = (alpha >= 0.f) ? -an : an;                // -sign(alpha)*norm
            g    = 1.f / (beta * (beta - alpha));            // tau/(alpha-beta)^2
        }
        if (c >= j) {
            float cb[16];
            #pragma unroll
            for (int k = 0; k < 16; ++k) cb[k] = cbuf[i0 + k];
            float wp = 0.f, Ajc = 0.f;
            #pragma unroll
            for (int k = 0; k < 16; ++k) {
                const int i = i0 + k;
                wp  = fmaf((i > j) ? cb[k] : 0.f, A[k], wp); // v0 (i>j) part
                Ajc += (i == j) ? A[k] : 0.f;                // A[j][c]
            }
            wp  += __shfl_xor(wp, 1);  wp  += __shfl_xor(wp, 2);
            Ajc += __shfl_xor(Ajc, 1); Ajc += __shfl_xor(Ajc, 2);
            const float amb = alpha - beta;
            const float gw  = g * (wp + amb * Ajc);          // g * v0^T A[:,c]
            #pragma unroll
            for (int k = 0; k < 16; ++k) {
                const int i = i0 + k;
                const float v0 = (i > j) ? cb[k] : ((i == j) ? amb : 0.f);
                A[k] = fmaf(-gw, v0, A[k]);
            }
            if (c == j + 1) {        // publish next column into the OTHER buffer
                #pragma unroll
                for (int k = 0; k < 16; ++k) colb[(j + 1) & 1][i0 + k] = A[k];
                float np = 0.f;
                #pragma unroll
                for (int k = 0; k < 16; ++k) {
                    const int i = i0 + k;
                    np = fmaf((i > j + 1) ? A[k] : 0.f, A[k], np);
                }
                np += __shfl_xor(np, 1); np += __shfl_xor(np, 2);
                if (q == 0) nrmb[(j + 1) & 1] = np;
            }
        }
        __syncthreads();
    }

    // ---- R to LDS, diag inverses/signs, qcol prologue ----
    #pragma unroll
    for (int k = 0; k < 16; ++k) Rs[(i0 + k) * 65 + c] = A[k];
    {
        float dv = 0.f;
        #pragma unroll
        for (int k = 0; k < 16; ++k) dv += (i0 + k == c) ? A[k] : 0.f;
        dv += __shfl_xor(dv, 1); dv += __shfl_xor(dv, 2);
        if (q == 0) dval[c] = dv;
    }
    if (c == 0) {
        #pragma unroll
        for (int k = 0; k < 16; ++k) qcol[0][i0 + k] = M[k];
    }
    __syncthreads();
    if (tid < 64) {
        const float d = dval[tid];
        dinv[tid] = 1.f / d;
        const float NZL2E = 0.51012934f;     // 64^-0.25 * log2(e)
        sgnNZ[tid] = (d >= 0.f) ? NZL2E : -NZL2E;
    }
    __syncthreads();

    // ---- solve Q R = M (column sweep, 1 barrier/step); write P rows ----
    #pragma unroll 1
    for (int j = 0; j < 64; ++j) {
        const float fdi = dinv[j];
        if (c >= j) {
            const float* qc = qcol[j & 1];
            float qq[16];
            #pragma unroll
            for (int k = 0; k < 16; ++k) qq[k] = qc[i0 + k];
            if (c == j) {            // P[h][e=j][f] = Q[f][j]*sign(R[f][f])*NZL2E
                #pragma unroll
                for (int k = 0; k < 16; ++k)
                    P[h * 4096 + j * 64 + i0 + k] = qq[k] * fdi * sgnNZ[i0 + k];
            } else {
                const float f = Rs[j * 65 + c] * fdi;
                #pragma unroll
                for (int k = 0; k < 16; ++k) M[k] = fmaf(-qq[k], f, M[k]);
                if (c == j + 1) {
                    #pragma unroll
                    for (int k = 0; k < 16; ++k) qcol[(j + 1) & 1][i0 + k] = M[k];
                }
            }
        }
        __syncthreads();
    }
}

// ---------------- FAVOR+ map: f16-split MFMA, 64-row tiles, no barriers -----
__global__ __launch_bounds__(256, 4) void favor_kernel(const float* __restrict__ data,
                                                       const float* __restrict__ P,
                                                       float* __restrict__ out)
{
    __shared__ __attribute__((aligned(16))) float SMEM[2 * 4096];   // 32 KB dbuf

    const int tid   = threadIdx.x;
    const int h     = blockIdx.x & 15;
    const int chunk = blockIdx.x >> 4;              // 0..63
    const size_t rowbase = (size_t)chunk * 1024;    // 16 tiles x 64 rows

    const int lane = tid & 63;
    const int wv   = tid >> 6;                      // wave owns rows 16wv..16wv+15
    const int ls   = lane & 15;                     // slot / A-row / C-col
    const int lg   = lane >> 4;                     // k-group / stage row-sub

    const float* db = data + (size_t)h * 64;

    // stage: linear LDS dest (gload_lds), XOR-pre-swizzled global source so
    // row r's logical 16B slot s lands at phys slot s^r  [rule 21]
#define STAGE(T, B) do {                                                           \
        const size_t rT_ = rowbase + (size_t)(T) * 64 + 16 * wv;                   \
        float* dst_ = SMEM + (B) * 4096 + wv * 1024;                               \
        _Pragma("unroll")                                                          \
        for (int i_ = 0; i_ < 4; ++i_) {                                           \
            const int rl_ = 4 * i_ + lg;                                           \
            gload16(db + (rT_ + (size_t)rl_) * 1024 + ((ls ^ rl_) << 2),           \
                    dst_ + i_ * 256);                                              \
        }                                                                          \
    } while (0)

    STAGE(0, 0);    // oldest in vmcnt order; B-load latency overlaps it

    // B fragments straight from global (L1-cached, shared by all waves/blocks
    // of this head). B[k][col]: col = n*16 + ls, k = kh*32 + lg*8 + j.
    f16x8 bh[4][2], bl[4][2];
    #pragma unroll
    for (int n = 0; n < 4; ++n) {
        #pragma unroll
        for (int kh = 0; kh < 2; ++kh) {
            #pragma unroll
            for (int j = 0; j < 8; ++j) {
                const float pv = P[h * 4096 + (kh * 32 + lg * 8 + j) * 64 + n * 16 + ls];
                const _Float16 hi = (_Float16)pv;
                bh[n][kh][j] = hi;
                bl[n][kh][j] = (_Float16)(pv - (float)hi);
            }
        }
    }

    const float SQS = 0.09016844005556021f;          // log2(e)/16
    #pragma unroll 1
    for (int t = 0; t < 16; ++t) {
        if (t < 15) STAGE(t + 1, (t + 1) & 1);
        // In-order vmcnt: retire tile-t loads (4), keep stores(t-1)[16] and
        // loads(t+1)[4] in flight.
        if (t == 0)       asm volatile("s_waitcnt vmcnt(4)"  ::: "memory");
        else if (t < 15)  asm volatile("s_waitcnt vmcnt(20)" ::: "memory");
        else              asm volatile("s_waitcnt vmcnt(16)" ::: "memory");

        const float* xr = SMEM + (t & 1) * 4096 + wv * 1024 + ls * 64;  // A-row ls

        // ---- A fragments (f16 hi/lo) + row sum-of-squares ----
        f16x8 ah[2], al[2];
        float sq = 0.f;
        #pragma unroll
        for (int kh = 0; kh < 2; ++kh) {
            const int s0 = (8 * kh + 2 * lg) ^ ls;       // swizzled 16B slots
            const int s1 = (8 * kh + 2 * lg + 1) ^ ls;
            const float4 va = *reinterpret_cast<const float4*>(xr + 4 * s0);
            const float4 vb = *reinterpret_cast<const float4*>(xr + 4 * s1);
            const float xs[8] = {va.x, va.y, va.z, va.w, vb.x, vb.y, vb.z, vb.w};
            #pragma unroll
            for (int j = 0; j < 8; ++j) {
                const float xv = xs[j];
                const _Float16 hi = (_Float16)xv;
                ah[kh][j] = hi;
                al[kh][j] = (_Float16)(xv - (float)hi);
                sq = fmaf(xv, xv, sq);
            }
        }
        sq += __shfl_xor(sq, 16);                        // complete 64-k sum
        sq += __shfl_xor(sq, 32);                        // (valid for row ls)

        // ---- 24 MFMAs: C = Xh*Bh + Xh*Bl + Xl*Bh ----
        f32x4 acc[4];
        #pragma unroll
        for (int n = 0; n < 4; ++n) {
            f32x4 a = {0.f, 0.f, 0.f, 0.f};
            #pragma unroll
            for (int kh = 0; kh < 2; ++kh) {
                a = __builtin_amdgcn_mfma_f32_16x16x32_f16(ah[kh], bh[n][kh], a, 0, 0, 0);
                a = __builtin_amdgcn_mfma_f32_16x16x32_f16(ah[kh], bl[n][kh], a, 0, 0, 0);
                a = __builtin_amdgcn_mfma_f32_16x16x32_f16(al[kh], bh[n][kh], a, 0, 0, 0);
            }
            acc[n] = a;
        }

        // ---- epilogue: C[row=4lg+reg][col=16n+ls], exp2 + eps, stores ----
        const size_t rowT = rowbase + (size_t)t * 64 + 16 * wv;
        #pragma unroll
        for (int reg = 0; reg < 4; ++reg) {
            const int row_i = 4 * lg + reg;
            const float sqr = __shfl(sq, row_i) * SQS;   // from lane ls = row_i
            float* orow = out + (rowT + (size_t)row_i) * 1024 + (size_t)h * 64 + ls;
            #pragma unroll
            for (int n = 0; n < 4; ++n)
                orow[16 * n] = EXP2F(acc[n][reg] - sqr) + 1e-6f;
        }
    }
#undef STAGE
}

extern "C" void kernel_launch(void* const* d_in, const int* in_sizes, int n_in,
                              void* d_out, int out_size, void* d_ws, size_t ws_size,
                              hipStream_t stream)
{
    const float* data = (const float*)d_in[0];   // (L,N,H,E) fp32
    const float* pm   = (const float*)d_in[1];   // (H,E,E)   fp32
    float* out = (float*)d_out;                  // (L,N,H,F) fp32
    float* P   = (float*)d_ws;                   // 16*64*64*4 = 256 KB scratch

    qr_kernel<<<16, 256, 0, stream>>>(pm, P);
    favor_kernel<<<1024, 256, 0, stream>>>(data, P, out);
}

// Round 10
// 189.580 us; speedup vs baseline: 1.0374x; 1.0374x over previous
//
#include <hip/hip_runtime.h>
#include <math.h>

// L=4096, N=16, H=16, E=64. rho = L*N = 65536 rows of 1024 floats (head h at +64h).
// out[rho][h][f] = exp2( x.Ps[h][:,f] - sq*SQS ) + 1e-6, Ps = proj*64^-.25*log2e.
// proj = q^T D, D = sign(diag(r)) of LAPACK-convention QR(pm[h]^T) (convention-
// dependent — must reproduce geqrf signs). Factor then Q = M R^-1.
// favor: f16 hi/lo split MFMA (C = Xh*Bh + Xh*Bl + Xl*Bh), residual ~2^-23.
// Round-10: C-tile transposed through the wave-private LDS strip -> 4x
// global_store_dwordx4 (256B segments) instead of 16x scalar (64B segments);
// r9 post-mortem showed the 64B-scatter write stream (1.7 TB/s) was the floor.

typedef _Float16 f16x8 __attribute__((ext_vector_type(8)));
typedef float    f32x4 __attribute__((ext_vector_type(4)));

#define AS1 __attribute__((address_space(1)))
#define AS3 __attribute__((address_space(3)))

#if __has_builtin(__builtin_amdgcn_exp2f)
#define EXP2F(x) __builtin_amdgcn_exp2f(x)
#else
#define EXP2F(x) exp2f(x)
#endif

static __device__ __forceinline__ void gload16(const float* g, float* l) {
    __builtin_amdgcn_global_load_lds((AS1 const void*)g, (AS3 void*)l, 16, 0, 0);
}

// ---------------- per-head QR (fp32 Householder, LAPACK dlarfg signs) -------
__global__ __launch_bounds__(256) void qr_kernel(const float* __restrict__ pm,
                                                 float* __restrict__ P)
{
    __shared__ float colb[2][64];
    __shared__ float nrmb[2];
    __shared__ float Rs[64 * 65];
    __shared__ float qcol[2][64];
    __shared__ float dval[64];
    __shared__ float dinv[64];
    __shared__ float sgnNZ[64];

    const int tid = threadIdx.x;
    const int h   = blockIdx.x;
    const int c   = tid >> 2;       // column 0..63 (quad = 4 consecutive lanes)
    const int q   = tid & 3;        // row-quarter
    const int i0  = q * 16;

    float A[16], M[16];             // A[k] = M[i0+k][c] = pm[h][c][i0+k]
    {
        const float4* src = reinterpret_cast<const float4*>(pm + h * 4096 + c * 64 + i0);
        #pragma unroll
        for (int k4 = 0; k4 < 4; ++k4) {
            const float4 v = src[k4];
            A[4*k4+0] = M[4*k4+0] = v.x;
            A[4*k4+1] = M[4*k4+1] = v.y;
            A[4*k4+2] = M[4*k4+2] = v.z;
            A[4*k4+3] = M[4*k4+3] = v.w;
        }
    }
    if (c == 0) {                    // publish column 0 + its sub-norm
        #pragma unroll
        for (int k = 0; k < 16; ++k) colb[0][i0 + k] = A[k];
        float np = 0.f;
        #pragma unroll
        for (int k = 0; k < 16; ++k) if (i0 + k >= 1) np = fmaf(A[k], A[k], np);
        np += __shfl_xor(np, 1); np += __shfl_xor(np, 2);
        if (q == 0) nrmb[0] = np;
    }
    __syncthreads();

    // ---- factor: 64 Householder steps, 1 barrier each ----
    #pragma unroll 1
    for (int j = 0; j < 64; ++j) {
        const float* cbuf = colb[j & 1];
        const float alpha = cbuf[j];
        const float nrm2  = nrmb[j & 1];
        float beta, g;
        if (nrm2 == 0.f) { beta = alpha; g = 0.f; }          // H = I, tau = 0
        else {
            const float an = sqrtf(fmaf(alpha, alpha, nrm2));
            beta = (alpha >= 0.f) ? -an : an;                // -sign(alpha)*norm
            g    = 1.f / (beta * (beta - alpha));            // tau/(alpha-beta)^2
        }
        if (c >= j) {
            float cb[16];
            #pragma unroll
            for (int k = 0; k < 16; ++k) cb[k] = cbuf[i0 + k];
            float wp = 0.f, Ajc = 0.f;
            #pragma unroll
            for (int k = 0; k < 16; ++k) {
                const int i = i0 + k;
                wp  = fmaf((i > j) ? cb[k] : 0.f, A[k], wp); // v0 (i>j) part
                Ajc += (i == j) ? A[k] : 0.f;                // A[j][c]
            }
            wp  += __shfl_xor(wp, 1);  wp  += __shfl_xor(wp, 2);
            Ajc += __shfl_xor(Ajc, 1); Ajc += __shfl_xor(Ajc, 2);
            const float amb = alpha - beta;
            const float gw  = g * (wp + amb * Ajc);          // g * v0^T A[:,c]
            #pragma unroll
            for (int k = 0; k < 16; ++k) {
                const int i = i0 + k;
                const float v0 = (i > j) ? cb[k] : ((i == j) ? amb : 0.f);
                A[k] = fmaf(-gw, v0, A[k]);
            }
            if (c == j + 1) {        // publish next column into the OTHER buffer
                #pragma unroll
                for (int k = 0; k < 16; ++k) colb[(j + 1) & 1][i0 + k] = A[k];
                float np = 0.f;
                #pragma unroll
                for (int k = 0; k < 16; ++k) {
                    const int i = i0 + k;
                    np = fmaf((i > j + 1) ? A[k] : 0.f, A[k], np);
                }
                np += __shfl_xor(np, 1); np += __shfl_xor(np, 2);
                if (q == 0) nrmb[(j + 1) & 1] = np;
            }
        }
        __syncthreads();
    }

    // ---- R to LDS, diag inverses/signs, qcol prologue ----
    #pragma unroll
    for (int k = 0; k < 16; ++k) Rs[(i0 + k) * 65 + c] = A[k];
    {
        float dv = 0.f;
        #pragma unroll
        for (int k = 0; k < 16; ++k) dv += (i0 + k == c) ? A[k] : 0.f;
        dv += __shfl_xor(dv, 1); dv += __shfl_xor(dv, 2);
        if (q == 0) dval[c] = dv;
    }
    if (c == 0) {
        #pragma unroll
        for (int k = 0; k < 16; ++k) qcol[0][i0 + k] = M[k];
    }
    __syncthreads();
    if (tid < 64) {
        const float d = dval[tid];
        dinv[tid] = 1.f / d;
        const float NZL2E = 0.51012934f;     // 64^-0.25 * log2(e)
        sgnNZ[tid] = (d >= 0.f) ? NZL2E : -NZL2E;
    }
    __syncthreads();

    // ---- solve Q R = M (column sweep, 1 barrier/step); write P rows ----
    #pragma unroll 1
    for (int j = 0; j < 64; ++j) {
        const float fdi = dinv[j];
        if (c >= j) {
            const float* qc = qcol[j & 1];
            float qq[16];
            #pragma unroll
            for (int k = 0; k < 16; ++k) qq[k] = qc[i0 + k];
            if (c == j) {            // P[h][e=j][f] = Q[f][j]*sign(R[f][f])*NZL2E
                #pragma unroll
                for (int k = 0; k < 16; ++k)
                    P[h * 4096 + j * 64 + i0 + k] = qq[k] * fdi * sgnNZ[i0 + k];
            } else {
                const float f = Rs[j * 65 + c] * fdi;
                #pragma unroll
                for (int k = 0; k < 16; ++k) M[k] = fmaf(-qq[k], f, M[k]);
                if (c == j + 1) {
                    #pragma unroll
                    for (int k = 0; k < 16; ++k) qcol[(j + 1) & 1][i0 + k] = M[k];
                }
            }
        }
        __syncthreads();
    }
}

// -------- FAVOR+ map: f16-split MFMA, LDS C-transpose, dwordx4 stores -------
__global__ __launch_bounds__(256, 4) void favor_kernel(const float* __restrict__ data,
                                                       const float* __restrict__ P,
                                                       float* __restrict__ out)
{
    __shared__ __attribute__((aligned(16))) float SMEM[2 * 4096];   // 32 KB dbuf

    const int tid   = threadIdx.x;
    const int h     = blockIdx.x & 15;
    const int chunk = blockIdx.x >> 4;              // 0..127
    const size_t rowbase = (size_t)chunk * 512;     // 8 tiles x 64 rows

    const int lane = tid & 63;
    const int wv   = tid >> 6;                      // wave owns rows 16wv..16wv+15
    const int ls   = lane & 15;                     // slot / A-row / C-col
    const int lg   = lane >> 4;                     // k-group / stage row-sub

    const float* db = data + (size_t)h * 64;

    // stage: linear LDS dest (gload_lds), XOR-pre-swizzled global source so
    // row r's logical 16B slot s lands at phys slot s^r  [rule 21]
#define STAGE(T, B) do {                                                           \
        const size_t rT_ = rowbase + (size_t)(T) * 64 + 16 * wv;                   \
        float* dst_ = SMEM + (B) * 4096 + wv * 1024;                               \
        _Pragma("unroll")                                                          \
        for (int i_ = 0; i_ < 4; ++i_) {                                           \
            const int rl_ = 4 * i_ + lg;                                           \
            gload16(db + (rT_ + (size_t)rl_) * 1024 + ((ls ^ rl_) << 2),           \
                    dst_ + i_ * 256);                                              \
        }                                                                          \
    } while (0)

    STAGE(0, 0);    // oldest in vmcnt order; B-load latency overlaps it

    // B fragments straight from global (L1/L2-cached, shared by all blocks of
    // this head). B[k][col]: col = n*16 + ls, k = kh*32 + lg*8 + j.
    f16x8 bh[4][2], bl[4][2];
    #pragma unroll
    for (int n = 0; n < 4; ++n) {
        #pragma unroll
        for (int kh = 0; kh < 2; ++kh) {
            #pragma unroll
            for (int j = 0; j < 8; ++j) {
                const float pv = P[h * 4096 + (kh * 32 + lg * 8 + j) * 64 + n * 16 + ls];
                const _Float16 hi = (_Float16)pv;
                bh[n][kh][j] = hi;
                bl[n][kh][j] = (_Float16)(pv - (float)hi);
            }
        }
    }

    const float SQS = 0.09016844005556021f;          // log2(e)/16
    #pragma unroll 1
    for (int t = 0; t < 8; ++t) {
        // keep program order: epilogue(t-1) LDS readback BEFORE this STAGE
        asm volatile("" ::: "memory");
        if (t < 7) STAGE(t + 1, (t + 1) & 1);
        // In-order vmcnt: retire tile-t loads (4), keep stores(t-1)[4] and
        // loads(t+1)[4] in flight.
        if (t == 0)      asm volatile("s_waitcnt vmcnt(4)" ::: "memory");
        else if (t < 7)  asm volatile("s_waitcnt vmcnt(8)" ::: "memory");
        else             asm volatile("s_waitcnt vmcnt(4)" ::: "memory");

        float* strip = SMEM + (t & 1) * 4096 + wv * 1024;   // wave-private 16x64
        const float* xr = strip + ls * 64;                  // A-row ls

        // ---- A fragments (f16 hi/lo) + row sum-of-squares ----
        f16x8 ah[2], al[2];
        float sq = 0.f;
        #pragma unroll
        for (int kh = 0; kh < 2; ++kh) {
            const int s0 = (8 * kh + 2 * lg) ^ ls;       // swizzled 16B slots
            const int s1 = (8 * kh + 2 * lg + 1) ^ ls;
            const float4 va = *reinterpret_cast<const float4*>(xr + 4 * s0);
            const float4 vb = *reinterpret_cast<const float4*>(xr + 4 * s1);
            const float xs[8] = {va.x, va.y, va.z, va.w, vb.x, vb.y, vb.z, vb.w};
            #pragma unroll
            for (int j = 0; j < 8; ++j) {
                const float xv = xs[j];
                const _Float16 hi = (_Float16)xv;
                ah[kh][j] = hi;
                al[kh][j] = (_Float16)(xv - (float)hi);
                sq = fmaf(xv, xv, sq);
            }
        }
        sq += __shfl_xor(sq, 16);                        // complete 64-k sum
        sq += __shfl_xor(sq, 32);                        // (valid for row ls)

        // ---- 24 MFMAs: C = Xh*Bh + Xh*Bl + Xl*Bh ----
        f32x4 acc[4];
        #pragma unroll
        for (int n = 0; n < 4; ++n) {
            f32x4 a = {0.f, 0.f, 0.f, 0.f};
            #pragma unroll
            for (int kh = 0; kh < 2; ++kh) {
                a = __builtin_amdgcn_mfma_f32_16x16x32_f16(ah[kh], bh[n][kh], a, 0, 0, 0);
                a = __builtin_amdgcn_mfma_f32_16x16x32_f16(ah[kh], bl[n][kh], a, 0, 0, 0);
                a = __builtin_amdgcn_mfma_f32_16x16x32_f16(al[kh], bh[n][kh], a, 0, 0, 0);
            }
            acc[n] = a;
        }

        // ---- epilogue: exp2 + eps, transpose C through own LDS strip,
        //      then 4x global_store_dwordx4 (4 rows x 256 B segments) ----
        // write C[row][f] at strip[row*64 + ((16n+ls)^(lg<<4))]  (2-way banks)
        #pragma unroll
        for (int reg = 0; reg < 4; ++reg) {
            const int row_i = 4 * lg + reg;
            const float sqr = __shfl(sq, row_i) * SQS;   // from lane ls = row_i
            #pragma unroll
            for (int n = 0; n < 4; ++n)
                strip[row_i * 64 + ((16 * n + ls) ^ (lg << 4))] =
                    EXP2F(acc[n][reg] - sqr) + 1e-6f;
        }
        // read back: lane(ls,lg), store s: row = 4s+lg, f0 = 4ls;
        // element (row,f) lives at f ^ ((row>>2)<<4) = f ^ (s<<4)
        const size_t rowT = rowbase + (size_t)t * 64 + 16 * wv;
        #pragma unroll
        for (int s = 0; s < 4; ++s) {
            const int row = 4 * s + lg;
            const float4 v = *reinterpret_cast<const float4*>(
                strip + row * 64 + ((4 * ls) ^ (s << 4)));
            *reinterpret_cast<float4*>(
                out + (rowT + (size_t)row) * 1024 + (size_t)h * 64 + 4 * ls) = v;
        }
    }
#undef STAGE
}

extern "C" void kernel_launch(void* const* d_in, const int* in_sizes, int n_in,
                              void* d_out, int out_size, void* d_ws, size_t ws_size,
                              hipStream_t stream)
{
    const float* data = (const float*)d_in[0];   // (L,N,H,E) fp32
    const float* pm   = (const float*)d_in[1];   // (H,E,E)   fp32
    float* out = (float*)d_out;                  // (L,N,H,F) fp32
    float* P   = (float*)d_ws;                   // 16*64*64*4 = 256 KB scratch

    qr_kernel<<<16, 256, 0, stream>>>(pm, P);
    favor_kernel<<<2048, 256, 0, stream>>>(data, P, out);
}